// Round 6
// baseline (2559.263 us; speedup 1.0000x reference)
//
#include <hip/hip_runtime.h>
#include <stdint.h>

// ---------------- problem constants ----------------
#define NBLK   256         // 1 block per CU
#define NTHR   1024        // 16 waves
#define ROWS   4           // batch rows per block (256*4 = 1024)
#define S      512
#define KSZ    (1024*512)  // floats per k-slot
#define NELEMF 524288.0f
#define CHB    32768       // bytes per weight chunk: [512 n][32 k] bf16, XOR-swizzled
#define NCHK   48          // chunks per f-eval (3 layers x 16)

typedef __attribute__((ext_vector_type(2))) float  f32x2;
typedef __attribute__((ext_vector_type(4))) float  f32x4;
typedef __attribute__((ext_vector_type(8))) short  short8;
typedef __attribute__((ext_vector_type(4))) short  s16x4;
typedef __attribute__((ext_vector_type(8))) __bf16 bf16x8;
union frag_u { short8 s; bf16x8 b; };

typedef const __attribute__((address_space(1))) void* gas_t;
typedef __attribute__((address_space(3))) void*       las_t;

// ---------------- d_ws layout (bytes) ----------------
#define CTR_OFF  0
#define RED_OFF  256                       // floats: d0[256] d1[256] d2[256] err[20][256]
#define WB_OFF   65536                     // bf16 [48 chunks][512 n][32 k] swizzled
#define YALT_OFF (WB_OFF + NCHK*CHB)       // f32 [1024][512] alternate-y
#define K_OFF    (YALT_OFF + KSZ*4)        // f32 [7][1024][512] k-slots

// dopri5 tableau
static __device__ const float C_A2[1] = {0.2f};
static __device__ const float C_A3[2] = {3.f/40.f, 9.f/40.f};
static __device__ const float C_A4[3] = {44.f/45.f, -56.f/15.f, 32.f/9.f};
static __device__ const float C_A5[4] = {19372.f/6561.f, -25360.f/2187.f, 64448.f/6561.f, -212.f/729.f};
static __device__ const float C_A6[5] = {9017.f/3168.f, -355.f/33.f, 46732.f/5247.f, 49.f/176.f, -5103.f/18656.f};
static __device__ const float C_B5[6] = {35.f/384.f, 0.f, 500.f/1113.f, 125.f/192.f, -2187.f/6784.f, 11.f/84.f};
#define E1f (71.f/57600.f)
#define E3f (-71.f/16695.f)
#define E4f (71.f/1920.f)
#define E5f (-17253.f/339200.f)
#define E6f (22.f/525.f)
#define E7f (-1.f/40.f)

#define WAITVM(n) asm volatile("s_waitcnt vmcnt(" #n ")" ::: "memory")
#define LGKM0     asm volatile("s_waitcnt lgkmcnt(0)" ::: "memory")
#define SB0       __builtin_amdgcn_sched_barrier(0)
#define BAR       __builtin_amdgcn_s_barrier()

__device__ __forceinline__ short f2bf(float f) {
  union { float f; uint32_t u; } v; v.f = f;
  uint32_t u = v.u;
  return (short)((u + 0x7fffu + ((u >> 16) & 1u)) >> 16);   // RNE
}

extern "C" __global__ void node_zero(unsigned char* ws) {
  if (threadIdx.x == 0) *(unsigned*)(ws + CTR_OFF) = 0u;
}

extern "C" __global__ void __launch_bounds__(NTHR, 4)
node_main(const float* __restrict__ x,
          const float* __restrict__ W1, const float* __restrict__ b1,
          const float* __restrict__ W2, const float* __restrict__ b2,
          const float* __restrict__ W3, const float* __restrict__ b3,
          float* __restrict__ out, unsigned char* __restrict__ wsb) {
  __shared__ short ring[4 * 16384];        // 128 KiB: 4-slot chunk ring (Phase A aliases tr)
  __shared__ short actS[2][ROWS][528];     // bf16 act ping/pong, stride 528
  __shared__ float sred[24];

  const int tid  = threadIdx.x;
  const int wg   = blockIdx.x;
  const int r0   = wg * ROWS;
  const int lane = tid & 63;
  const int wv   = tid >> 6;               // 0..15
  const int m16  = lane & 15;
  const int kg   = lane >> 4;              // 0..3
  const int n0   = wv * 32;                // 32 output cols per wave
  const int rot  = wg & 15;                // per-CU K-chunk skew
  const int arowB = (m16 & 3) * 1056;      // act row byte offset
  const unsigned usB = (unsigned)((kg ^ (m16 & 3)) * 16);   // B swizzle unit offset
  const unsigned bcolB = (unsigned)(n0 + m16) * 64u;

  unsigned* ctr = (unsigned*)(wsb + CTR_OFF);
  float*    red = (float*)(wsb + RED_OFF);
  char*     Wbb = (char*)(wsb + WB_OFF);
  float*    yAb = (float*)(wsb + YALT_OFF);
  float*    kb  = (float*)(wsb + K_OFF);

  // per-thread 2-float slot of the block's 4x512 slice
  const int srow = tid >> 8;               // 0..3
  const int scol = (tid & 255) * 2;        // 0..510
  const size_t soff = (size_t)(r0 + srow) * S + scol;

  const float b1v0 = b1[n0 + m16], b1v1 = b1[n0 + 16 + m16];
  const float b2v0 = b2[n0 + m16], b2v1 = b2[n0 + 16 + m16];
  const float b3v0 = b3[n0 + m16], b3v1 = b3[n0 + 16 + m16];

  unsigned gt = NBLK;
  float* yloc = out;
  float* yAlt = yAb;
  int s1s = 0, s7s = 6;

  // ---------- grid barrier ----------
  auto gbar = [&]() {
    __threadfence(); __syncthreads();
    if (tid == 0) {
      __hip_atomic_fetch_add(ctr, 1u, __ATOMIC_ACQ_REL, __HIP_MEMORY_SCOPE_AGENT);
      while (__hip_atomic_load(ctr, __ATOMIC_ACQUIRE, __HIP_MEMORY_SCOPE_AGENT) < gt)
        __builtin_amdgcn_s_sleep(2);
    }
    __syncthreads();
    if ((tid & 63) == 0)
      (void)__hip_atomic_load(ctr, __ATOMIC_ACQUIRE, __HIP_MEMORY_SCOPE_AGENT);
    __syncthreads();
    gt += NBLK;
  };

  auto block_sum = [&](float v) -> float {
    #pragma unroll
    for (int o = 32; o > 0; o >>= 1) v += __shfl_down(v, o, 64);
    if ((tid & 63) == 0) sred[tid >> 6] = v;
    __syncthreads();
    if (tid == 0) {
      float s = 0.f;
      for (int i = 0; i < 16; ++i) s += sred[i];
      sred[16] = s;
    }
    __syncthreads();
    float r = sred[16];
    __syncthreads();
    return r;
  };

  auto grid_sum = [&](const float* base) -> float {
    float v = (tid < NBLK) ? base[tid] : 0.f;
    return block_sum(v);
  };

  // DMA one 32 KB chunk (pipeline position p) into ring slot p&3
  auto stagep = [&](int p) {
    const int lp = p >> 4;
    const int kcp = (p + rot) & 15;
    const char* gsrc = Wbb + (size_t)(lp * 16 + kcp) * CHB + (size_t)tid * 16;
    char* ldst = (char*)ring + (size_t)(p & 3) * CHB + (size_t)tid * 16;
    __builtin_amdgcn_global_load_lds((gas_t)(uintptr_t)gsrc,
                                     (las_t)(uint32_t)(uintptr_t)ldst, 16, 0, 0);
    __builtin_amdgcn_global_load_lds((gas_t)(uintptr_t)(gsrc + 16384),
                                     (las_t)(uint32_t)(uintptr_t)(ldst + 16384), 16, 0, 0);
  };

  // ---------- one f-eval: build y_stage -> 48-chunk DMA pipeline -> k-slot ----------
  auto feval = [&](const float* coef, int nk, float dtc, float* kout, float* y5p) {
    // build own slice of y_stage (global reads, compiler-waited)
    f32x2 v = *(const f32x2*)(yloc + soff);
    for (int j = 0; j < nk; ++j) {
      const float cc = coef[j];
      if (cc == 0.f) continue;
      const int slot = (j == 0) ? s1s : j;
      v += (cc * dtc) * *(const f32x2*)(kb + (size_t)slot * KSZ + soff);
    }
    if (y5p) *(f32x2*)(y5p + soff) = v;
    {
      unsigned u = ((unsigned)(unsigned short)f2bf(v[1]) << 16) |
                   (unsigned)(unsigned short)f2bf(v[0]);
      *(unsigned*)((char*)&actS[0][0][0] + srow * 1056 + scol * 2) = u;
    }
    // prologue: 3 chunks in flight
    stagep(0); stagep(1); stagep(2);
    SB0;

    f32x4 acc0 = {0.f, 0.f, 0.f, 0.f}, acc1 = {0.f, 0.f, 0.f, 0.f};
    #pragma unroll
    for (int g = 0; g < NCHK; ++g) {
      LGKM0; SB0;                            // my ds ops (reads of g-1, act writes) retired
      if (g < NCHK - 2)      { WAITVM(4); }  // chunk g landed; g+1,g+2 in flight
      else if (g == NCHK - 2){ WAITVM(2); }
      else                   { WAITVM(0); }
      SB0; BAR;                              // block-wide: g visible, slot of g-1 free
      if (g + 3 < NCHK) stagep(g + 3);       // enqueue immediately (slot (g-1)&3)
      {
        const int lp = g >> 4;
        const int kc = (g + rot) & 15;
        const short* sb = ring + (g & 3) * (CHB / 2);
        const char* aBuf = (const char*)&actS[0][0][0] + ((lp == 1) ? 4224 : 0);
        frag_u a; a.s = *(const short8*)(aBuf + arowB + kc * 64 + kg * 16);
        const char* bp = (const char*)sb + bcolB + usB;
        frag_u bq0; bq0.s = *(const short8*)bp;
        frag_u bq1; bq1.s = *(const short8*)(bp + 1024);
        acc0 = __builtin_amdgcn_mfma_f32_16x16x32_bf16(a.b, bq0.b, acc0, 0, 0, 0);
        acc1 = __builtin_amdgcn_mfma_f32_16x16x32_bf16(a.b, bq1.b, acc1, 0, 0, 0);
      }
      if (g == 15 || g == 31) {              // layer boundary: relu + act swap
        const float bA = (g == 15) ? b1v0 : b2v0;
        const float bB = (g == 15) ? b1v1 : b2v1;
        char* aNext = (char*)&actS[0][0][0] + ((g == 15) ? 4224 : 0);
        if (kg == 0) {
          #pragma unroll
          for (int r = 0; r < 4; ++r) {
            *(short*)(aNext + r * 1056 + (n0 + m16) * 2)      = f2bf(fmaxf(acc0[r] + bA, 0.f));
            *(short*)(aNext + r * 1056 + (n0 + 16 + m16) * 2) = f2bf(fmaxf(acc1[r] + bB, 0.f));
          }
        }
        acc0 = f32x4{0.f, 0.f, 0.f, 0.f};
        acc1 = f32x4{0.f, 0.f, 0.f, 0.f};
        // visibility handled by next iteration's LGKM0 + BAR
      }
    }
    // layer-2 epilogue: k output (f32, global)
    if (kg == 0) {
      #pragma unroll
      for (int r = 0; r < 4; ++r) {
        kout[(size_t)(r0 + r) * S + n0 + m16]      = acc0[r] + b3v0;
        kout[(size_t)(r0 + r) * S + n0 + 16 + m16] = acc1[r] + b3v1;
      }
    }
    __syncthreads();   // full drain; k-slot slice visible block-wide
  };

  // ---- Phase A: y0 = [x,0] (own slice) + weight repack (192 blocks) ----
  {
    f32x2 vv;
    if (scol < 448) vv = *(const f32x2*)(x + (size_t)(r0 + srow) * 448 + scol);
    else            vv = f32x2{0.f, 0.f};
    *(f32x2*)(yloc + soff) = vv;
  }
  if (wg < 192) {
    float (*tr)[68] = (float (*)[68])ring;   // alias, Phase A only
    const int layerI = wg >> 6;
    const int sub = wg & 63;
    const float* W = (layerI == 0) ? W1 : ((layerI == 1) ? W2 : W3);
    const int tk = (sub >> 3) * 64, tn = (sub & 7) * 64;
    {
      const int lr = tid >> 4, lc = (tid & 15) * 4;
      f32x4 a = *(const f32x4*)(W + (size_t)(tk + lr) * S + tn + lc);
      #pragma unroll
      for (int e = 0; e < 4; ++e) tr[lr][lc + e] = a[e];
    }
    __syncthreads();
    {
      const int n = tid & 63, g4 = tid >> 6;          // g4: 0..15, 4 k each
      s16x4 p;
      #pragma unroll
      for (int j = 0; j < 4; ++j) p[j] = f2bf(tr[g4 * 4 + j][n]);
      const int ncol = tn + n;
      const int kk = tk + g4 * 4;
      const int kc = kk >> 5;                         // chunk within layer (0..15)
      const unsigned u = (unsigned)((kk & 31) >> 3);
      const unsigned h = (unsigned)((kk >> 2) & 1);
      size_t byte = (size_t)(layerI * 16 + kc) * CHB
                  + (size_t)ncol * 64
                  + ((u ^ (unsigned)(ncol & 3)) * 16u + h * 8u);
      *(s16x4*)(Wbb + byte) = p;
    }
    __syncthreads();
  }
  gbar();                                                    // barrier 1

  // ---- f0 -> slot0; d0, d1 ----
  feval(nullptr, 0, 0.f, kb, nullptr);
  {
    f32x2 y = *(const f32x2*)(yloc + soff);
    f32x2 f = *(const f32x2*)(kb + soff);
    float ay = 0.f, af = 0.f;
    #pragma unroll
    for (int q = 0; q < 2; ++q) {
      float sc = 1e-3f + 1e-3f * fabsf(y[q]);
      float a = y[q] / sc, b = f[q] / sc;
      ay += a * a; af += b * b;
    }
    float p0 = block_sum(ay);
    float p1 = block_sum(af);
    if (tid == 0) { red[wg] = p0; red[NBLK + wg] = p1; }
  }
  gbar();                                                    // barrier 2
  float d1s, h0;
  {
    float a = grid_sum(red);
    float b = grid_sum(red + NBLK);
    float d0 = sqrtf(a / NELEMF); d1s = sqrtf(b / NELEMF);
    h0 = (fminf(d0, d1s) < 1e-5f) ? 1e-6f : 0.01f * d0 / fmaxf(d1s, 1e-12f);
  }

  // ---- f1 = f(y0 + h0*f0) -> slot1; d2 ----
  {
    const float onec[1] = {1.f};
    feval(onec, 1, h0, kb + (size_t)1 * KSZ, nullptr);
  }
  {
    f32x2 y  = *(const f32x2*)(yloc + soff);
    f32x2 f0 = *(const f32x2*)(kb + soff);
    f32x2 f1 = *(const f32x2*)(kb + (size_t)1 * KSZ + soff);
    float acc2 = 0.f;
    #pragma unroll
    for (int q = 0; q < 2; ++q) {
      float sc = 1e-3f + 1e-3f * fabsf(y[q]);
      float d = (f1[q] - f0[q]) / sc;
      acc2 += d * d;
    }
    float p2 = block_sum(acc2);
    if (tid == 0) red[2 * NBLK + wg] = p2;
  }
  gbar();                                                    // barrier 3
  float dt;
  {
    float s = grid_sum(red + 2 * NBLK);
    float d2 = sqrtf(s / NELEMF) / h0;
    float dmax = fmaxf(d1s, d2);
    float h1 = (dmax <= 1e-15f) ? fmaxf(1e-6f, h0 * 1e-3f)
                                : powf(0.01f / fmaxf(dmax, 1e-12f), 0.2f);
    dt = fminf(fminf(100.f * h0, h1), 1.f);
  }

  // ---- integration loop (6 f-evals/step; B5-stage eval IS the FSAL k7) ----
  float tcur = 0.f;
  int done = 0;
  for (int step = 0; step < 20; ++step) {
    const float dtc = fminf(dt, 1.f - tcur);
    feval(C_A2, 1, dtc, kb + (size_t)1 * KSZ, nullptr);
    feval(C_A3, 2, dtc, kb + (size_t)2 * KSZ, nullptr);
    feval(C_A4, 3, dtc, kb + (size_t)3 * KSZ, nullptr);
    feval(C_A5, 4, dtc, kb + (size_t)4 * KSZ, nullptr);
    feval(C_A6, 5, dtc, kb + (size_t)5 * KSZ, nullptr);
    feval(C_B5, 6, dtc, kb + (size_t)s7s * KSZ, yAlt);   // y5 -> yAlt; k7 -> s7s

    {
      f32x2 yv  = *(const f32x2*)(yloc + soff);
      f32x2 y5v = *(const f32x2*)(yAlt + soff);
      f32x2 k1v = *(const f32x2*)(kb + (size_t)s1s * KSZ + soff);
      f32x2 k3v = *(const f32x2*)(kb + (size_t)2   * KSZ + soff);
      f32x2 k4v = *(const f32x2*)(kb + (size_t)3   * KSZ + soff);
      f32x2 k5v = *(const f32x2*)(kb + (size_t)4   * KSZ + soff);
      f32x2 k6v = *(const f32x2*)(kb + (size_t)5   * KSZ + soff);
      f32x2 k7v = *(const f32x2*)(kb + (size_t)s7s * KSZ + soff);
      f32x2 e = E1f * k1v + E3f * k3v + E4f * k4v + E5f * k5v + E6f * k6v + E7f * k7v;
      float acc2 = 0.f;
      #pragma unroll
      for (int q = 0; q < 2; ++q) {
        float ee = dtc * e[q];
        float sc = 1e-3f + 1e-3f * fmaxf(fabsf(yv[q]), fabsf(y5v[q]));
        float rr = ee / sc;
        acc2 += rr * rr;
      }
      float p = block_sum(acc2);
      if (tid == 0) red[3 * NBLK + step * NBLK + wg] = p;
    }
    gbar();                                                  // per-step barrier
    float err_norm = sqrtf(grid_sum(red + 3 * NBLK + step * NBLK) / NELEMF);

    const int accept = (err_norm <= 1.0f);
    const float en = fmaxf(err_norm, 1e-10f);
    float fac = 0.9f * powf(en, -0.2f);
    fac = fminf(fmaxf(fac, 0.2f), 10.0f);
    const float dt_next = dtc * fac;
    const int done_new = done | (accept && (tcur + dtc >= 1.f - 1e-7f));
    if (!done) {
      if (accept) {
        tcur += dtc;
        float* tp = yloc; yloc = yAlt; yAlt = tp;
        int ts = s1s; s1s = s7s; s7s = ts;
      }
      dt = dt_next;
    }
    done = done_new;
    if (done) break;
  }

  // ---- final: ensure result slice is in d_out ----
  if (yloc != out) {
    *(f32x2*)(out + soff) = *(const f32x2*)(yloc + soff);
  }
}

extern "C" void kernel_launch(void* const* d_in, const int* in_sizes, int n_in,
                              void* d_out, int out_size, void* d_ws, size_t ws_size,
                              hipStream_t stream) {
  const float* x  = (const float*)d_in[0];
  const float* W1 = (const float*)d_in[1];
  const float* b1 = (const float*)d_in[2];
  const float* W2 = (const float*)d_in[3];
  const float* b2 = (const float*)d_in[4];
  const float* W3 = (const float*)d_in[5];
  const float* b3 = (const float*)d_in[6];
  unsigned char* ws = (unsigned char*)d_ws;

  hipLaunchKernelGGL(node_zero, dim3(1), dim3(64), 0, stream, ws);
  hipLaunchKernelGGL(node_main, dim3(NBLK), dim3(NTHR), 0, stream,
                     x, W1, b1, W2, b2, W3, b3, (float*)d_out, ws);
}

// Round 7
// 1414.808 us; speedup vs baseline: 1.8089x; 1.8089x over previous
//
#include <hip/hip_runtime.h>
#include <stdint.h>

// ---------------- problem constants ----------------
#define NBLK   256         // 1 block per CU
#define NTHR   1024        // 16 waves
#define ROWS   4           // batch rows per block (256*4 = 1024)
#define S      512
#define KSZ    (1024*512)  // floats per k-slot
#define NELEMF 524288.0f
#define CHB4   4096        // bytes per wave chunk: [32 n][64 k] bf16, XOR-swizzled
#define PANB   32768       // bytes per wave panel per layer (8 chunks)
#define LAYB   524288      // bytes per layer (16 wave panels)

typedef __attribute__((ext_vector_type(2))) float  f32x2;
typedef __attribute__((ext_vector_type(4))) float  f32x4;
typedef __attribute__((ext_vector_type(8))) short  short8;
typedef __attribute__((ext_vector_type(4))) short  s16x4;
typedef __attribute__((ext_vector_type(8))) __bf16 bf16x8;
union frag_u { short8 s; bf16x8 b; };

typedef const __attribute__((address_space(1))) void* gas_t;
typedef __attribute__((address_space(3))) void*       las_t;

// ---------------- d_ws layout (bytes) ----------------
#define CTR_OFF  0
#define RED_OFF  256                       // floats: d0[256] d1[256] d2[256] err[20][256]
#define WB_OFF   65536                     // bf16 [3 layer][16 wave][8 ch][32 n][64 k] swizzled
#define YALT_OFF (WB_OFF + 3*LAYB)         // f32 [1024][512] alternate-y
#define K_OFF    (YALT_OFF + KSZ*4)        // f32 [7][1024][512] k-slots

// dopri5 tableau
static __device__ const float C_A2[1] = {0.2f};
static __device__ const float C_A3[2] = {3.f/40.f, 9.f/40.f};
static __device__ const float C_A4[3] = {44.f/45.f, -56.f/15.f, 32.f/9.f};
static __device__ const float C_A5[4] = {19372.f/6561.f, -25360.f/2187.f, 64448.f/6561.f, -212.f/729.f};
static __device__ const float C_A6[5] = {9017.f/3168.f, -355.f/33.f, 46732.f/5247.f, 49.f/176.f, -5103.f/18656.f};
static __device__ const float C_B5[6] = {35.f/384.f, 0.f, 500.f/1113.f, 125.f/192.f, -2187.f/6784.f, 11.f/84.f};
#define E1f (71.f/57600.f)
#define E3f (-71.f/16695.f)
#define E4f (71.f/1920.f)
#define E5f (-17253.f/339200.f)
#define E6f (22.f/525.f)
#define E7f (-1.f/40.f)

#define WAITVM(n) asm volatile("s_waitcnt vmcnt(" #n ")" ::: "memory")
#define LGKM0     asm volatile("s_waitcnt lgkmcnt(0)" ::: "memory")
#define SB0       __builtin_amdgcn_sched_barrier(0)
#define BAR       __builtin_amdgcn_s_barrier()

__device__ __forceinline__ short f2bf(float f) {
  union { float f; uint32_t u; } v; v.f = f;
  uint32_t u = v.u;
  return (short)((u + 0x7fffu + ((u >> 16) & 1u)) >> 16);   // RNE
}

extern "C" __global__ void node_zero(unsigned char* ws) {
  if (threadIdx.x == 0) *(unsigned*)(ws + CTR_OFF) = 0u;
}

extern "C" __global__ void __launch_bounds__(NTHR)
node_main(const float* __restrict__ x,
          const float* __restrict__ W1, const float* __restrict__ b1,
          const float* __restrict__ W2, const float* __restrict__ b2,
          const float* __restrict__ W3, const float* __restrict__ b3,
          float* __restrict__ out, unsigned char* __restrict__ wsb) {
  __shared__ char  ringC[16 * 8192];       // 128 KiB: per-wave 2-slot rings (Phase A aliases tr)
  __shared__ short actS[2][ROWS][528];     // bf16 act ping/pong, stride 528
  __shared__ float sred[24];

  const int tid  = threadIdx.x;
  const int wg   = blockIdx.x;
  const int r0   = wg * ROWS;
  const int lane = tid & 63;
  const int wv   = tid >> 6;               // 0..15
  const int m16  = lane & 15;
  const int kg   = lane >> 4;              // 0..3
  const int n0   = wv * 32;                // 32 output cols per wave

  unsigned* ctr = (unsigned*)(wsb + CTR_OFF);
  float*    red = (float*)(wsb + RED_OFF);
  char*     Wbb = (char*)(wsb + WB_OFF);
  float*    yAb = (float*)(wsb + YALT_OFF);
  float*    kb  = (float*)(wsb + K_OFF);

  // per-wave DMA bases (lane*16 part encodes the hw lane scatter)
  const char* wbase = Wbb + (size_t)wv * PANB + (size_t)lane * 16;
  char*       lbase = ringC + (size_t)wv * 8192 + (size_t)lane * 16;

  // per-lane LDS read bases
  const int o0 = ((kg ^ (m16 & 7)) << 4);            // B unit offset, kk=0
  const char* rb0 = ringC + wv * 8192 + m16 * 128 + o0;
  const char* rb1 = ringC + wv * 8192 + m16 * 128 + (o0 ^ 64);  // kk=1
  const char* aB  = (const char*)&actS[0][0][0] + (m16 & 3) * 1056 + kg * 16;
  char*       actBytes = (char*)&actS[0][0][0];

  // per-thread 2-float slot of the block's 4x512 slice
  const int srow = tid >> 8;               // 0..3
  const int scol = (tid & 255) * 2;        // 0..510
  const size_t soff = (size_t)(r0 + srow) * S + scol;

  const float b1v0 = b1[n0 + m16], b1v1 = b1[n0 + 16 + m16];
  const float b2v0 = b2[n0 + m16], b2v1 = b2[n0 + 16 + m16];
  const float b3v0 = b3[n0 + m16], b3v1 = b3[n0 + 16 + m16];

  unsigned gt = NBLK;
  float* yloc = out;
  float* yAlt = yAb;
  int s1s = 0, s7s = 6;

  // ---------- grid barrier ----------
  auto gbar = [&]() {
    __threadfence(); __syncthreads();
    if (tid == 0) {
      __hip_atomic_fetch_add(ctr, 1u, __ATOMIC_ACQ_REL, __HIP_MEMORY_SCOPE_AGENT);
      while (__hip_atomic_load(ctr, __ATOMIC_ACQUIRE, __HIP_MEMORY_SCOPE_AGENT) < gt)
        __builtin_amdgcn_s_sleep(2);
    }
    __syncthreads();
    if ((tid & 63) == 0)
      (void)__hip_atomic_load(ctr, __ATOMIC_ACQUIRE, __HIP_MEMORY_SCOPE_AGENT);
    __syncthreads();
    gt += NBLK;
  };

  auto block_sum = [&](float v) -> float {
    #pragma unroll
    for (int o = 32; o > 0; o >>= 1) v += __shfl_down(v, o, 64);
    if ((tid & 63) == 0) sred[tid >> 6] = v;
    __syncthreads();
    if (tid == 0) {
      float s = 0.f;
      for (int i = 0; i < 16; ++i) s += sred[i];
      sred[16] = s;
    }
    __syncthreads();
    float r = sred[16];
    __syncthreads();
    return r;
  };

  auto grid_sum = [&](const float* base) -> float {
    float v = (tid < NBLK) ? base[tid] : 0.f;
    return block_sum(v);
  };

  // wave-private DMA: one 4 KB chunk (pipeline pos p) into own ring slot p&1
  auto stagep = [&](int p) {
    const int lp = p >> 3, ch = p & 7;
    const char* g = wbase + (size_t)lp * LAYB + ch * CHB4;
    char* l = lbase + (p & 1) * CHB4;
    #pragma unroll
    for (int i = 0; i < 4; ++i)
      __builtin_amdgcn_global_load_lds((gas_t)(uintptr_t)(g + i * 1024),
                                       (las_t)(uint32_t)(uintptr_t)(l + i * 1024),
                                       16, 0, 0);
  };

  // ---------- one f-eval: act build -> 24 wave-private chunks -> k-slot ----------
  auto feval = [&](const float* coef, int nk, float dtc, float* kout, float* y5p) {
    f32x2 v = *(const f32x2*)(yloc + soff);
    for (int j = 0; j < nk; ++j) {
      const float cc = coef[j];
      if (cc == 0.f) continue;
      const int slot = (j == 0) ? s1s : j;
      v += (cc * dtc) * *(const f32x2*)(kb + (size_t)slot * KSZ + soff);
    }
    if (y5p) *(f32x2*)(y5p + soff) = v;
    {
      unsigned u = ((unsigned)(unsigned short)f2bf(v[1]) << 16) |
                   (unsigned)(unsigned short)f2bf(v[0]);
      *(unsigned*)(actBytes + srow * 1056 + scol * 2) = u;
    }
    stagep(0); stagep(1);       // wave's own pipeline starts (8 loads in flight)
    LGKM0; SB0; BAR;            // act visible block-wide (vmcnt NOT drained)

    f32x4 acc0 = {0.f, 0.f, 0.f, 0.f}, acc1 = {0.f, 0.f, 0.f, 0.f};
    #pragma unroll
    for (int p = 0; p < 24; ++p) {
      if (p < 23) { WAITVM(4); } else { WAITVM(0); }   // own chunk p landed
      SB0;
      {
        const int bufB = (p >= 8 && p < 16) ? 4224 : 0;
        const int ch = p & 7;
        frag_u a0; a0.s = *(const short8*)(aB + bufB + ch * 128);
        frag_u a1; a1.s = *(const short8*)(aB + bufB + ch * 128 + 64);
        const int sB = (p & 1) * CHB4;
        frag_u b00; b00.s = *(const short8*)(rb0 + sB);
        frag_u b01; b01.s = *(const short8*)(rb0 + sB + 2048);
        frag_u b10; b10.s = *(const short8*)(rb1 + sB);
        frag_u b11; b11.s = *(const short8*)(rb1 + sB + 2048);
        acc0 = __builtin_amdgcn_mfma_f32_16x16x32_bf16(a0.b, b00.b, acc0, 0, 0, 0);
        acc1 = __builtin_amdgcn_mfma_f32_16x16x32_bf16(a0.b, b01.b, acc1, 0, 0, 0);
        acc0 = __builtin_amdgcn_mfma_f32_16x16x32_bf16(a1.b, b10.b, acc0, 0, 0, 0);
        acc1 = __builtin_amdgcn_mfma_f32_16x16x32_bf16(a1.b, b11.b, acc1, 0, 0, 0);
      }
      LGKM0; SB0;                         // own reads of slot p&1 retired
      if (p + 2 < 24) stagep(p + 2);      // refill own freed slot
      if (p == 7 || p == 15) {            // layer boundary: relu + act swap
        const float bA = (p == 7) ? b1v0 : b2v0;
        const float bB = (p == 7) ? b1v1 : b2v1;
        char* aNext = actBytes + ((p == 7) ? 4224 : 0);
        if (kg == 0) {
          #pragma unroll
          for (int r = 0; r < 4; ++r) {
            *(short*)(aNext + r * 1056 + (n0 + m16) * 2)      = f2bf(fmaxf(acc0[r] + bA, 0.f));
            *(short*)(aNext + r * 1056 + (n0 + 16 + m16) * 2) = f2bf(fmaxf(acc1[r] + bB, 0.f));
          }
        }
        acc0 = f32x4{0.f, 0.f, 0.f, 0.f};
        acc1 = f32x4{0.f, 0.f, 0.f, 0.f};
        LGKM0; SB0; BAR;                  // act writes visible (vmcnt NOT drained)
      }
    }
    // layer-2 epilogue: k output (f32, global)
    if (kg == 0) {
      #pragma unroll
      for (int r = 0; r < 4; ++r) {
        kout[(size_t)(r0 + r) * S + n0 + m16]      = acc0[r] + b3v0;
        kout[(size_t)(r0 + r) * S + n0 + 16 + m16] = acc1[r] + b3v1;
      }
    }
    __syncthreads();   // full drain; k slice visible; act buf reusable
  };

  // ---- Phase A: y0 = [x,0] (own slice) + weight repack (192 blocks) ----
  {
    f32x2 vv;
    if (scol < 448) vv = *(const f32x2*)(x + (size_t)(r0 + srow) * 448 + scol);
    else            vv = f32x2{0.f, 0.f};
    *(f32x2*)(yloc + soff) = vv;
  }
  if (wg < 192) {
    float (*tr)[68] = (float (*)[68])ringC;   // alias, Phase A only
    const int layerI = wg >> 6;
    const int sub = wg & 63;
    const float* W = (layerI == 0) ? W1 : ((layerI == 1) ? W2 : W3);
    const int tk = (sub >> 3) * 64, tn = (sub & 7) * 64;
    {
      const int lr = tid >> 4, lc = (tid & 15) * 4;
      f32x4 a = *(const f32x4*)(W + (size_t)(tk + lr) * S + tn + lc);
      #pragma unroll
      for (int e = 0; e < 4; ++e) tr[lr][lc + e] = a[e];
    }
    __syncthreads();
    {
      const int n = tid & 63, g4 = tid >> 6;          // g4: 0..15, 4 k each
      s16x4 p;
      #pragma unroll
      for (int j = 0; j < 4; ++j) p[j] = f2bf(tr[g4 * 4 + j][n]);
      const int ncol = tn + n;
      const int kk = tk + g4 * 4;                     // k base of this 4-pack
      const unsigned unit = (unsigned)((kk & 63) >> 3);
      const unsigned half = (unsigned)((kk >> 2) & 1);
      size_t byte = (size_t)layerI * LAYB + (size_t)(ncol >> 5) * PANB
                  + (size_t)((kk >> 6) & 7) * CHB4
                  + (size_t)(ncol & 31) * 128
                  + ((unit ^ (unsigned)(ncol & 7)) << 4) + half * 8;
      *(s16x4*)(Wbb + byte) = p;
    }
    __syncthreads();
  }
  gbar();                                                    // barrier 1

  // ---- f0 -> slot0; d0, d1 ----
  feval(nullptr, 0, 0.f, kb, nullptr);
  {
    f32x2 y = *(const f32x2*)(yloc + soff);
    f32x2 f = *(const f32x2*)(kb + soff);
    float ay = 0.f, af = 0.f;
    #pragma unroll
    for (int q = 0; q < 2; ++q) {
      float sc = 1e-3f + 1e-3f * fabsf(y[q]);
      float a = y[q] / sc, b = f[q] / sc;
      ay += a * a; af += b * b;
    }
    float p0 = block_sum(ay);
    float p1 = block_sum(af);
    if (tid == 0) { red[wg] = p0; red[NBLK + wg] = p1; }
  }
  gbar();                                                    // barrier 2
  float d1s, h0;
  {
    float a = grid_sum(red);
    float b = grid_sum(red + NBLK);
    float d0 = sqrtf(a / NELEMF); d1s = sqrtf(b / NELEMF);
    h0 = (fminf(d0, d1s) < 1e-5f) ? 1e-6f : 0.01f * d0 / fmaxf(d1s, 1e-12f);
  }

  // ---- f1 = f(y0 + h0*f0) -> slot1; d2 ----
  {
    const float onec[1] = {1.f};
    feval(onec, 1, h0, kb + (size_t)1 * KSZ, nullptr);
  }
  {
    f32x2 y  = *(const f32x2*)(yloc + soff);
    f32x2 f0 = *(const f32x2*)(kb + soff);
    f32x2 f1 = *(const f32x2*)(kb + (size_t)1 * KSZ + soff);
    float acc2 = 0.f;
    #pragma unroll
    for (int q = 0; q < 2; ++q) {
      float sc = 1e-3f + 1e-3f * fabsf(y[q]);
      float d = (f1[q] - f0[q]) / sc;
      acc2 += d * d;
    }
    float p2 = block_sum(acc2);
    if (tid == 0) red[2 * NBLK + wg] = p2;
  }
  gbar();                                                    // barrier 3
  float dt;
  {
    float s = grid_sum(red + 2 * NBLK);
    float d2 = sqrtf(s / NELEMF) / h0;
    float dmax = fmaxf(d1s, d2);
    float h1 = (dmax <= 1e-15f) ? fmaxf(1e-6f, h0 * 1e-3f)
                                : powf(0.01f / fmaxf(dmax, 1e-12f), 0.2f);
    dt = fminf(fminf(100.f * h0, h1), 1.f);
  }

  // ---- integration loop (6 f-evals/step; B5-stage eval IS the FSAL k7) ----
  float tcur = 0.f;
  int done = 0;
  for (int step = 0; step < 20; ++step) {
    const float dtc = fminf(dt, 1.f - tcur);
    feval(C_A2, 1, dtc, kb + (size_t)1 * KSZ, nullptr);
    feval(C_A3, 2, dtc, kb + (size_t)2 * KSZ, nullptr);
    feval(C_A4, 3, dtc, kb + (size_t)3 * KSZ, nullptr);
    feval(C_A5, 4, dtc, kb + (size_t)4 * KSZ, nullptr);
    feval(C_A6, 5, dtc, kb + (size_t)5 * KSZ, nullptr);
    feval(C_B5, 6, dtc, kb + (size_t)s7s * KSZ, yAlt);   // y5 -> yAlt; k7 -> s7s

    {
      f32x2 yv  = *(const f32x2*)(yloc + soff);
      f32x2 y5v = *(const f32x2*)(yAlt + soff);
      f32x2 k1v = *(const f32x2*)(kb + (size_t)s1s * KSZ + soff);
      f32x2 k3v = *(const f32x2*)(kb + (size_t)2   * KSZ + soff);
      f32x2 k4v = *(const f32x2*)(kb + (size_t)3   * KSZ + soff);
      f32x2 k5v = *(const f32x2*)(kb + (size_t)4   * KSZ + soff);
      f32x2 k6v = *(const f32x2*)(kb + (size_t)5   * KSZ + soff);
      f32x2 k7v = *(const f32x2*)(kb + (size_t)s7s * KSZ + soff);
      f32x2 e = E1f * k1v + E3f * k3v + E4f * k4v + E5f * k5v + E6f * k6v + E7f * k7v;
      float acc2 = 0.f;
      #pragma unroll
      for (int q = 0; q < 2; ++q) {
        float ee = dtc * e[q];
        float sc = 1e-3f + 1e-3f * fmaxf(fabsf(yv[q]), fabsf(y5v[q]));
        float rr = ee / sc;
        acc2 += rr * rr;
      }
      float p = block_sum(acc2);
      if (tid == 0) red[3 * NBLK + step * NBLK + wg] = p;
    }
    gbar();                                                  // per-step barrier
    float err_norm = sqrtf(grid_sum(red + 3 * NBLK + step * NBLK) / NELEMF);

    const int accept = (err_norm <= 1.0f);
    const float en = fmaxf(err_norm, 1e-10f);
    float fac = 0.9f * powf(en, -0.2f);
    fac = fminf(fmaxf(fac, 0.2f), 10.0f);
    const float dt_next = dtc * fac;
    const int done_new = done | (accept && (tcur + dtc >= 1.f - 1e-7f));
    if (!done) {
      if (accept) {
        tcur += dtc;
        float* tp = yloc; yloc = yAlt; yAlt = tp;
        int ts = s1s; s1s = s7s; s7s = ts;
      }
      dt = dt_next;
    }
    done = done_new;
    if (done) break;
  }

  // ---- final: ensure result slice is in d_out ----
  if (yloc != out) {
    *(f32x2*)(out + soff) = *(const f32x2*)(yloc + soff);
  }
}

extern "C" void kernel_launch(void* const* d_in, const int* in_sizes, int n_in,
                              void* d_out, int out_size, void* d_ws, size_t ws_size,
                              hipStream_t stream) {
  const float* x  = (const float*)d_in[0];
  const float* W1 = (const float*)d_in[1];
  const float* b1 = (const float*)d_in[2];
  const float* W2 = (const float*)d_in[3];
  const float* b2 = (const float*)d_in[4];
  const float* W3 = (const float*)d_in[5];
  const float* b3 = (const float*)d_in[6];
  unsigned char* ws = (unsigned char*)d_ws;

  hipLaunchKernelGGL(node_zero, dim3(1), dim3(64), 0, stream, ws);
  hipLaunchKernelGGL(node_main, dim3(NBLK), dim3(NTHR), 0, stream,
                     x, W1, b1, W2, b2, W3, b3, (float*)d_out, ws);
}

// Round 8
// 788.513 us; speedup vs baseline: 3.2457x; 1.7943x over previous
//
#include <hip/hip_runtime.h>
#include <stdint.h>

// ---------------- problem constants ----------------
#define NBLK   256         // 1 block per CU
#define NTHR   512         // 8 waves (halved vs R5: cheaper lockstep barriers)
#define ROWS   4           // batch rows per block (256*4 = 1024)
#define S      512
#define KSZ    (1024*512)  // floats per k-slot
#define NELEMF 524288.0f
#define CHB    65536       // bytes per weight chunk: [512 n][64 k] bf16, XOR-swizzled
#define NCHK   24          // chunks per f-eval (3 layers x 8)

typedef __attribute__((ext_vector_type(4))) float  f32x4;
typedef __attribute__((ext_vector_type(8))) short  short8;
typedef __attribute__((ext_vector_type(4))) short  s16x4;
typedef __attribute__((ext_vector_type(8))) __bf16 bf16x8;
union frag_u { short8 s; bf16x8 b; };

typedef const __attribute__((address_space(1))) void* gas_t;
typedef __attribute__((address_space(3))) void*       las_t;

// ---------------- d_ws layout (bytes) ----------------
#define CTR_OFF  0
#define RED_OFF  256                       // floats: d0[256] d1[256] d2[256] err[20][256]
#define WB_OFF   65536                     // bf16 [24 chunks][512 n][64 k] swizzled
#define YALT_OFF (WB_OFF + NCHK*CHB)       // f32 [1024][512] alternate-y
#define K_OFF    (YALT_OFF + KSZ*4)        // f32 [7][1024][512] k-slots

// dopri5 tableau
static __device__ const float C_A2[1] = {0.2f};
static __device__ const float C_A3[2] = {3.f/40.f, 9.f/40.f};
static __device__ const float C_A4[3] = {44.f/45.f, -56.f/15.f, 32.f/9.f};
static __device__ const float C_A5[4] = {19372.f/6561.f, -25360.f/2187.f, 64448.f/6561.f, -212.f/729.f};
static __device__ const float C_A6[5] = {9017.f/3168.f, -355.f/33.f, 46732.f/5247.f, 49.f/176.f, -5103.f/18656.f};
static __device__ const float C_B5[6] = {35.f/384.f, 0.f, 500.f/1113.f, 125.f/192.f, -2187.f/6784.f, 11.f/84.f};
#define E1f (71.f/57600.f)
#define E3f (-71.f/16695.f)
#define E4f (71.f/1920.f)
#define E5f (-17253.f/339200.f)
#define E6f (22.f/525.f)
#define E7f (-1.f/40.f)

#define WAITVM(n) asm volatile("s_waitcnt vmcnt(" #n ")" ::: "memory")
#define LGKM0     asm volatile("s_waitcnt lgkmcnt(0)" ::: "memory")
#define SB0       __builtin_amdgcn_sched_barrier(0)
#define BAR       __builtin_amdgcn_s_barrier()

__device__ __forceinline__ short f2bf(float f) {
  union { float f; uint32_t u; } v; v.f = f;
  uint32_t u = v.u;
  return (short)((u + 0x7fffu + ((u >> 16) & 1u)) >> 16);   // RNE
}

extern "C" __global__ void node_zero(unsigned char* ws) {
  if (threadIdx.x == 0) *(unsigned*)(ws + CTR_OFF) = 0u;
}

extern "C" __global__ void __launch_bounds__(NTHR)
node_main(const float* __restrict__ x,
          const float* __restrict__ W1, const float* __restrict__ b1,
          const float* __restrict__ W2, const float* __restrict__ b2,
          const float* __restrict__ W3, const float* __restrict__ b3,
          float* __restrict__ out, unsigned char* __restrict__ wsb) {
  __shared__ short ring[2 * 32768];        // 128 KiB: 2-slot chunk ring (Phase A aliases tr)
  __shared__ short actS[2][ROWS][528];     // bf16 act ping/pong, stride 528
  __shared__ float sred[24];

  const int tid  = threadIdx.x;
  const int wg   = blockIdx.x;
  const int r0   = wg * ROWS;
  const int lane = tid & 63;
  const int wv   = tid >> 6;               // 0..7
  const int m16  = lane & 15;
  const int kg   = lane >> 4;              // 0..3
  const int n0   = wv * 64;                // 64 output cols per wave (4 n-tiles)
  const int arowB = (m16 & 3) * 1056;      // act row byte offset
  const unsigned m7 = (unsigned)(m16 & 7);
  const unsigned bcolB = (unsigned)(n0 + m16) * 128u;

  unsigned* ctr = (unsigned*)(wsb + CTR_OFF);
  float*    red = (float*)(wsb + RED_OFF);
  char*     Wbb = (char*)(wsb + WB_OFF);
  float*    yAb = (float*)(wsb + YALT_OFF);
  float*    kb  = (float*)(wsb + K_OFF);

  // per-thread 4-float slot of the block's 4x512 slice
  const int srow = tid >> 7;               // 0..3
  const int scol = (tid & 127) * 4;        // 0..508
  const size_t soff = (size_t)(r0 + srow) * S + scol;

  float b1v[4], b2v[4], b3v[4];
  #pragma unroll
  for (int nt = 0; nt < 4; ++nt) {
    b1v[nt] = b1[n0 + nt * 16 + m16];
    b2v[nt] = b2[n0 + nt * 16 + m16];
    b3v[nt] = b3[n0 + nt * 16 + m16];
  }

  unsigned gt = NBLK;
  float* yloc = out;
  float* yAlt = yAb;
  int s1s = 0, s7s = 6;

  // ---------- grid barrier ----------
  auto gbar = [&]() {
    __threadfence(); __syncthreads();
    if (tid == 0) {
      __hip_atomic_fetch_add(ctr, 1u, __ATOMIC_ACQ_REL, __HIP_MEMORY_SCOPE_AGENT);
      while (__hip_atomic_load(ctr, __ATOMIC_ACQUIRE, __HIP_MEMORY_SCOPE_AGENT) < gt)
        __builtin_amdgcn_s_sleep(2);
    }
    __syncthreads();
    if ((tid & 63) == 0)
      (void)__hip_atomic_load(ctr, __ATOMIC_ACQUIRE, __HIP_MEMORY_SCOPE_AGENT);
    __syncthreads();
    gt += NBLK;
  };

  auto block_sum = [&](float v) -> float {
    #pragma unroll
    for (int o = 32; o > 0; o >>= 1) v += __shfl_down(v, o, 64);
    if ((tid & 63) == 0) sred[tid >> 6] = v;
    __syncthreads();
    if (tid == 0) {
      float s = 0.f;
      for (int i = 0; i < 8; ++i) s += sred[i];
      sred[8] = s;
    }
    __syncthreads();
    float r = sred[8];
    __syncthreads();
    return r;
  };

  auto grid_sum = [&](const float* base) -> float {
    float v = (tid < NBLK) ? base[tid] : 0.f;
    return block_sum(v);
  };

  // DMA one 64 KB chunk into ring slot g&1: 512 thr x 16 B x 8 rounds, linear
  auto stage = [&](int g) {
    const char* gsrc = Wbb + (size_t)g * CHB + (size_t)tid * 16;
    char* ldst = (char*)ring + (size_t)(g & 1) * CHB + (size_t)tid * 16;
    #pragma unroll
    for (int r = 0; r < 8; ++r)
      __builtin_amdgcn_global_load_lds((gas_t)(uintptr_t)(gsrc + r * 8192),
                                       (las_t)(uint32_t)(uintptr_t)(ldst + r * 8192),
                                       16, 0, 0);
  };

  // ---------- one f-eval: build y_stage -> 24-chunk DMA pipeline -> k-slot ----------
  auto feval = [&](const float* coef, int nk, float dtc, float* kout, float* y5p) {
    // build own slice of y_stage
    f32x4 v = *(const f32x4*)(yloc + soff);
    for (int j = 0; j < nk; ++j) {
      const float cc = coef[j];
      if (cc == 0.f) continue;
      const int slot = (j == 0) ? s1s : j;
      v += (cc * dtc) * *(const f32x4*)(kb + (size_t)slot * KSZ + soff);
    }
    if (y5p) *(f32x4*)(y5p + soff) = v;
    // start the weight pipeline
    stage(0); stage(1);
    {
      s16x4 pk;
      #pragma unroll
      for (int e = 0; e < 4; ++e) pk[e] = f2bf(v[e]);
      *(s16x4*)((char*)&actS[0][0][0] + srow * 1056 + scol * 2) = pk;
    }
    LGKM0; SB0; BAR;      // act visible block-wide (vmcnt NOT drained)

    f32x4 acc[4];
    #pragma unroll
    for (int nt = 0; nt < 4; ++nt) acc[nt] = f32x4{0.f, 0.f, 0.f, 0.f};

    for (int g = 0; g < NCHK; ++g) {
      if (g < NCHK - 1) { WAITVM(8); } else { WAITVM(0); }   // chunk g landed
      SB0; BAR;
      {
        const short* sb = ring + (g & 1) * 32768;
        const char* aBuf = (const char*)&actS[(g >= 8 && g < 16) ? 1 : 0][0][0];
        const int kb2 = (g & 7) * 128;
        #pragma unroll
        for (int kt = 0; kt < 2; ++kt) {
          frag_u a; a.s = *(const short8*)(aBuf + arowB + kb2 + kt * 64 + kg * 16);
          const unsigned uu = (((unsigned)(kt * 4 + kg)) ^ m7) * 16u;
          const char* bp = (const char*)sb + bcolB + uu;
          #pragma unroll
          for (int nt = 0; nt < 4; ++nt) {
            frag_u bq; bq.s = *(const short8*)(bp + nt * 2048);
            acc[nt] = __builtin_amdgcn_mfma_f32_16x16x32_bf16(a.b, bq.b, acc[nt], 0, 0, 0);
          }
        }
      }
      LGKM0; SB0; BAR;                       // all waves done reading slot g&1
      if (g < NCHK - 2) stage(g + 2);        // refill freed slot
      if (g == 7 || g == 15) {               // layer boundary: relu + act swap
        char* aNext = (char*)&actS[(g == 7) ? 1 : 0][0][0];
        if (kg == 0) {
          #pragma unroll
          for (int nt = 0; nt < 4; ++nt) {
            const float bv = (g == 7) ? b1v[nt] : b2v[nt];
            #pragma unroll
            for (int r = 0; r < 4; ++r)
              *(short*)(aNext + r * 1056 + (n0 + nt * 16 + m16) * 2) =
                  f2bf(fmaxf(acc[nt][r] + bv, 0.f));
          }
        }
        #pragma unroll
        for (int nt = 0; nt < 4; ++nt) acc[nt] = f32x4{0.f, 0.f, 0.f, 0.f};
        LGKM0; SB0; BAR;                     // act writes visible
      }
    }
    // layer-2 epilogue: k output (f32, global)
    if (kg == 0) {
      #pragma unroll
      for (int nt = 0; nt < 4; ++nt) {
        #pragma unroll
        for (int r = 0; r < 4; ++r)
          kout[(size_t)(r0 + r) * S + n0 + nt * 16 + m16] = acc[nt][r] + b3v[nt];
      }
    }
    __syncthreads();   // full drain; k-slot slice visible block-wide
  };

  // ---- Phase A: y0 = [x,0] (own slice) + weight repack (192 blocks) ----
  {
    f32x4 vv;
    if (scol < 448) vv = *(const f32x4*)(x + (size_t)(r0 + srow) * 448 + scol);
    else            vv = f32x4{0.f, 0.f, 0.f, 0.f};
    *(f32x4*)(yloc + soff) = vv;
  }
  if (wg < 192) {
    float (*tr)[68] = (float (*)[68])ring;   // alias, Phase A only
    const int layerI = wg >> 6;
    const int sub = wg & 63;
    const float* W = (layerI == 0) ? W1 : ((layerI == 1) ? W2 : W3);
    const int tk = (sub >> 3) * 64, tn = (sub & 7) * 64;
    {
      const int lr = tid >> 3, lc = (tid & 7) * 8;
      const f32x4* src = (const f32x4*)(W + (size_t)(tk + lr) * S + tn + lc);
      f32x4 a = src[0], b = src[1];
      #pragma unroll
      for (int e = 0; e < 4; ++e) { tr[lr][lc + e] = a[e]; tr[lr][lc + 4 + e] = b[e]; }
    }
    __syncthreads();
    {
      const int n = tid & 63;
      #pragma unroll
      for (int j2 = 0; j2 < 2; ++j2) {
        const int g4 = (tid >> 6) + j2 * 8;           // 0..15, 4 k each
        s16x4 p;
        #pragma unroll
        for (int j = 0; j < 4; ++j) p[j] = f2bf(tr[g4 * 4 + j][n]);
        const int ncol = tn + n;
        const int kk = tk + g4 * 4;
        const int kc = kk >> 6;                       // chunk within layer
        const unsigned u = (unsigned)((kk & 63) >> 3);
        const unsigned h = (unsigned)((kk >> 2) & 1);
        size_t byte = ((size_t)(layerI * 8 + kc) * 512 + ncol) * 128
                    + ((u ^ (unsigned)(ncol & 7)) * 16u + h * 8u);
        *(s16x4*)(Wbb + byte) = p;
      }
    }
    __syncthreads();
  }
  gbar();                                                    // barrier 1

  // ---- f0 -> slot0; d0, d1 ----
  feval(nullptr, 0, 0.f, kb, nullptr);
  {
    f32x4 y = *(const f32x4*)(yloc + soff);
    f32x4 f = *(const f32x4*)(kb + soff);
    float ay = 0.f, af = 0.f;
    #pragma unroll
    for (int q = 0; q < 4; ++q) {
      float sc = 1e-3f + 1e-3f * fabsf(y[q]);
      float a = y[q] / sc, b = f[q] / sc;
      ay += a * a; af += b * b;
    }
    float p0 = block_sum(ay);
    float p1 = block_sum(af);
    if (tid == 0) { red[wg] = p0; red[NBLK + wg] = p1; }
  }
  gbar();                                                    // barrier 2
  float d1s, h0;
  {
    float a = grid_sum(red);
    float b = grid_sum(red + NBLK);
    float d0 = sqrtf(a / NELEMF); d1s = sqrtf(b / NELEMF);
    h0 = (fminf(d0, d1s) < 1e-5f) ? 1e-6f : 0.01f * d0 / fmaxf(d1s, 1e-12f);
  }

  // ---- f1 = f(y0 + h0*f0) -> slot1; d2 ----
  {
    const float onec[1] = {1.f};
    feval(onec, 1, h0, kb + (size_t)1 * KSZ, nullptr);
  }
  {
    f32x4 y  = *(const f32x4*)(yloc + soff);
    f32x4 f0 = *(const f32x4*)(kb + soff);
    f32x4 f1 = *(const f32x4*)(kb + (size_t)1 * KSZ + soff);
    float acc2 = 0.f;
    #pragma unroll
    for (int q = 0; q < 4; ++q) {
      float sc = 1e-3f + 1e-3f * fabsf(y[q]);
      float d = (f1[q] - f0[q]) / sc;
      acc2 += d * d;
    }
    float p2 = block_sum(acc2);
    if (tid == 0) red[2 * NBLK + wg] = p2;
  }
  gbar();                                                    // barrier 3
  float dt;
  {
    float s = grid_sum(red + 2 * NBLK);
    float d2 = sqrtf(s / NELEMF) / h0;
    float dmax = fmaxf(d1s, d2);
    float h1 = (dmax <= 1e-15f) ? fmaxf(1e-6f, h0 * 1e-3f)
                                : powf(0.01f / fmaxf(dmax, 1e-12f), 0.2f);
    dt = fminf(fminf(100.f * h0, h1), 1.f);
  }

  // ---- integration loop (6 f-evals/step; B5-stage eval IS the FSAL k7) ----
  float tcur = 0.f;
  int done = 0;
  for (int step = 0; step < 20; ++step) {
    const float dtc = fminf(dt, 1.f - tcur);
    feval(C_A2, 1, dtc, kb + (size_t)1 * KSZ, nullptr);
    feval(C_A3, 2, dtc, kb + (size_t)2 * KSZ, nullptr);
    feval(C_A4, 3, dtc, kb + (size_t)3 * KSZ, nullptr);
    feval(C_A5, 4, dtc, kb + (size_t)4 * KSZ, nullptr);
    feval(C_A6, 5, dtc, kb + (size_t)5 * KSZ, nullptr);
    feval(C_B5, 6, dtc, kb + (size_t)s7s * KSZ, yAlt);   // y5 -> yAlt; k7 -> s7s

    {
      f32x4 yv  = *(const f32x4*)(yloc + soff);
      f32x4 y5v = *(const f32x4*)(yAlt + soff);
      f32x4 k1v = *(const f32x4*)(kb + (size_t)s1s * KSZ + soff);
      f32x4 k3v = *(const f32x4*)(kb + (size_t)2   * KSZ + soff);
      f32x4 k4v = *(const f32x4*)(kb + (size_t)3   * KSZ + soff);
      f32x4 k5v = *(const f32x4*)(kb + (size_t)4   * KSZ + soff);
      f32x4 k6v = *(const f32x4*)(kb + (size_t)5   * KSZ + soff);
      f32x4 k7v = *(const f32x4*)(kb + (size_t)s7s * KSZ + soff);
      f32x4 e = E1f * k1v + E3f * k3v + E4f * k4v + E5f * k5v + E6f * k6v + E7f * k7v;
      float acc2 = 0.f;
      #pragma unroll
      for (int q = 0; q < 4; ++q) {
        float ee = dtc * e[q];
        float sc = 1e-3f + 1e-3f * fmaxf(fabsf(yv[q]), fabsf(y5v[q]));
        float rr = ee / sc;
        acc2 += rr * rr;
      }
      float p = block_sum(acc2);
      if (tid == 0) red[3 * NBLK + step * NBLK + wg] = p;
    }
    gbar();                                                  // per-step barrier
    float err_norm = sqrtf(grid_sum(red + 3 * NBLK + step * NBLK) / NELEMF);

    const int accept = (err_norm <= 1.0f);
    const float en = fmaxf(err_norm, 1e-10f);
    float fac = 0.9f * powf(en, -0.2f);
    fac = fminf(fmaxf(fac, 0.2f), 10.0f);
    const float dt_next = dtc * fac;
    const int done_new = done | (accept && (tcur + dtc >= 1.f - 1e-7f));
    if (!done) {
      if (accept) {
        tcur += dtc;
        float* tp = yloc; yloc = yAlt; yAlt = tp;
        int ts = s1s; s1s = s7s; s7s = ts;
      }
      dt = dt_next;
    }
    done = done_new;
    if (done) break;
  }

  // ---- final: ensure result slice is in d_out ----
  if (yloc != out) {
    *(f32x4*)(out + soff) = *(const f32x4*)(yloc + soff);
  }
}

extern "C" void kernel_launch(void* const* d_in, const int* in_sizes, int n_in,
                              void* d_out, int out_size, void* d_ws, size_t ws_size,
                              hipStream_t stream) {
  const float* x  = (const float*)d_in[0];
  const float* W1 = (const float*)d_in[1];
  const float* b1 = (const float*)d_in[2];
  const float* W2 = (const float*)d_in[3];
  const float* b2 = (const float*)d_in[4];
  const float* W3 = (const float*)d_in[5];
  const float* b3 = (const float*)d_in[6];
  unsigned char* ws = (unsigned char*)d_ws;

  hipLaunchKernelGGL(node_zero, dim3(1), dim3(64), 0, stream, ws);
  hipLaunchKernelGGL(node_main, dim3(NBLK), dim3(NTHR), 0, stream,
                     x, W1, b1, W2, b2, W3, b3, (float*)d_out, ws);
}